// Round 6
// baseline (58.231 us; speedup 1.0000x reference)
//
#include <hip/hip_runtime.h>
#include <math.h>

#define BB 4
#define NQ 256
#define NK 1024
#define DD 256
#define HH 256

// ---------------- K1: Projection GEMM (fp32) + E=exp(2x) epilogue ----------
// E[m,h] = exp(2*clamp(sum_d A[m,d]*W[d,h], -8, 8)).
// tanh(z) = 1 - 2/(1+e^{2z}) applied implicitly downstream; sum_h w_h const
// cancels in softmax. Fully-masked K-tiles exit early.
// Double-buffered, ONE barrier per k-step (dbuf makes the 2nd redundant).
#define TM 64
#define TN 64
#define TKK 16
#define NT (DD / TKK)   // 16 k-steps

__global__ __launch_bounds__(256) void proj_exp_kernel(
    const float* __restrict__ Q, const float* __restrict__ K,
    const float* __restrict__ Wq, const float* __restrict__ Wk,
    const int* __restrict__ vlen,
    float* __restrict__ Eq, float* __restrict__ Ek)
{
    const int QTILES = (BB * NQ) / TM;   // 16
    int bx = blockIdx.x;
    const float* A; const float* W; float* C; int bm;
    if (bx < QTILES) { A = Q; W = Wq; C = Eq; bm = bx * TM; }
    else {
        int kt = bx - QTILES;            // 0..63
        int b = kt >> 4;
        int lr = (kt & 15) * TM;         // batch-local row start
        if (lr >= vlen[b]) return;       // fully masked K-tile: skip
        A = K; W = Wk; C = Ek; bm = kt * TM;
    }
    int bn = blockIdx.y * TN;

    __shared__ float As[2][TKK][TM + 4];
    __shared__ float Ws[2][TKK][TN + 4];

    int tid = threadIdx.x;
    int ar = tid >> 2, ac4 = tid & 3;
    int wkk = tid >> 4, wc4 = tid & 15;
    int ty = tid >> 4, tx = tid & 15;

    float4 aR = *(const float4*)&A[(size_t)(bm + ar) * DD + ac4 * 4];
    float4 wR = *(const float4*)&W[(size_t)wkk * HH + bn + wc4 * 4];

    float acc[4][4] = {};

    for (int t = 0; t < NT; ++t) {
        int cur = t & 1;
        As[cur][ac4 * 4 + 0][ar] = aR.x;
        As[cur][ac4 * 4 + 1][ar] = aR.y;
        As[cur][ac4 * 4 + 2][ar] = aR.z;
        As[cur][ac4 * 4 + 3][ar] = aR.w;
        *(float4*)&Ws[cur][wkk][wc4 * 4] = wR;
        if (t + 1 < NT) {
            int k0 = (t + 1) * TKK;
            aR = *(const float4*)&A[(size_t)(bm + ar) * DD + k0 + ac4 * 4];
            wR = *(const float4*)&W[(size_t)(k0 + wkk) * HH + bn + wc4 * 4];
        }
        __syncthreads();
#pragma unroll
        for (int kk = 0; kk < TKK; ++kk) {
            float4 a4 = *(const float4*)&As[cur][kk][ty * 4];
            float4 w4 = *(const float4*)&Ws[cur][kk][tx * 4];
            acc[0][0] = fmaf(a4.x, w4.x, acc[0][0]);
            acc[0][1] = fmaf(a4.x, w4.y, acc[0][1]);
            acc[0][2] = fmaf(a4.x, w4.z, acc[0][2]);
            acc[0][3] = fmaf(a4.x, w4.w, acc[0][3]);
            acc[1][0] = fmaf(a4.y, w4.x, acc[1][0]);
            acc[1][1] = fmaf(a4.y, w4.y, acc[1][1]);
            acc[1][2] = fmaf(a4.y, w4.z, acc[1][2]);
            acc[1][3] = fmaf(a4.y, w4.w, acc[1][3]);
            acc[2][0] = fmaf(a4.z, w4.x, acc[2][0]);
            acc[2][1] = fmaf(a4.z, w4.y, acc[2][1]);
            acc[2][2] = fmaf(a4.z, w4.z, acc[2][2]);
            acc[2][3] = fmaf(a4.z, w4.w, acc[2][3]);
            acc[3][0] = fmaf(a4.w, w4.x, acc[3][0]);
            acc[3][1] = fmaf(a4.w, w4.y, acc[3][1]);
            acc[3][2] = fmaf(a4.w, w4.z, acc[3][2]);
            acc[3][3] = fmaf(a4.w, w4.w, acc[3][3]);
        }
        // no trailing barrier: next iter writes the OTHER buffer; writes to
        // this buffer recur only after the next barrier (all threads past
        // compute of this iter by then).
    }

#pragma unroll
    for (int i = 0; i < 4; ++i) {
        int m = bm + ty * 4 + i;
        float4 o;
        // clamp +-8: |tanh| error < 2.4e-7, keeps E and quad-products finite
        o.x = __expf(2.f * fminf(fmaxf(acc[i][0], -8.f), 8.f));
        o.y = __expf(2.f * fminf(fmaxf(acc[i][1], -8.f), 8.f));
        o.z = __expf(2.f * fminf(fmaxf(acc[i][2], -8.f), 8.f));
        o.w = __expf(2.f * fminf(fmaxf(acc[i][3], -8.f), 8.f));
        *(float4*)&C[(size_t)m * HH + bn + tx * 4] = o;
    }
}

// ---------------- K2: scores -> P = exp(-2T) + per-chunk row sums -----------
// T(q,k) = sum_h w_h/(1+Eq_h*Ek_h); logit = -2T. h staged in 4 chunks of 64
// (double-buffered, reg-prefetched, 1 barrier/chunk) -> ~36 KB LDS ->
// ~4 blocks/CU instead of 2. Quad-batched rational: one v_rcp per 4 h-terms.
#define HC 64
#define NHCH (HH / HC)   // 4

__global__ __launch_bounds__(256) void scores_kernel(
    const float* __restrict__ Eq, const float* __restrict__ Ek,
    const float* __restrict__ wv, const int* __restrict__ vlen,
    float* __restrict__ P, float* __restrict__ Psum)
{
    __shared__ __align__(16) float sQ[2][32][HC + 4];
    __shared__ __align__(16) float sK[2][32][HC + 4];
    __shared__ __align__(16) float sW[HH];

    int bid = blockIdx.x;
    int b = bid & 3;                 // batch-interleaved for balance
    int rest = bid >> 2;
    int qc = rest & 7;               // 8 q-chunks of 32
    int kc = rest >> 3;              // 32 k-chunks of 32
    int L = vlen[b];
    int k0 = kc * 32;
    if (k0 >= L) return;             // fully masked chunk: uniform exit
    int q0 = qc * 32;

    int tid = threadIdx.x;
    int lr = tid >> 3;               // 0..31 staging row
    int lc = tid & 7;                // f4 cols lc and lc+8

    const float* gq = Eq + ((size_t)b * NQ + q0 + lr) * HH;
    const float* gk = Ek + ((size_t)b * NK + k0 + lr) * HH;

    float4 q1 = *(const float4*)&gq[lc * 4];
    float4 q2 = *(const float4*)&gq[lc * 4 + 32];
    float4 k1 = *(const float4*)&gk[lc * 4];
    float4 k2 = *(const float4*)&gk[lc * 4 + 32];
    sW[tid] = wv[tid];               // covered by chunk-0 barrier

    int ki = tid & 15, qi = tid >> 4;
    float a00 = 0.f, a01 = 0.f, a10 = 0.f, a11 = 0.f;

    for (int c = 0; c < NHCH; ++c) {
        int cur = c & 1;
        *(float4*)&sQ[cur][lr][lc * 4] = q1;
        *(float4*)&sQ[cur][lr][lc * 4 + 32] = q2;
        *(float4*)&sK[cur][lr][lc * 4] = k1;
        *(float4*)&sK[cur][lr][lc * 4 + 32] = k2;
        if (c + 1 < NHCH) {
            int h0 = (c + 1) * HC;
            q1 = *(const float4*)&gq[h0 + lc * 4];
            q2 = *(const float4*)&gq[h0 + lc * 4 + 32];
            k1 = *(const float4*)&gk[h0 + lc * 4];
            k2 = *(const float4*)&gk[h0 + lc * 4 + 32];
        }
        __syncthreads();

#pragma unroll
        for (int h4 = 0; h4 < HC / 4; ++h4) {
            float4 w = *(const float4*)&sW[c * HC + h4 * 4];
            float wxy = w.x + w.y, wzw = w.z + w.w;
            float4 A0 = *(const float4*)&sQ[cur][qi][h4 * 4];
            float4 A1 = *(const float4*)&sQ[cur][qi + 16][h4 * 4];
            float4 B0 = *(const float4*)&sK[cur][ki][h4 * 4];
            float4 B1 = *(const float4*)&sK[cur][ki + 16][h4 * 4];
#define QUAD(acc, Aq, Bk)                                                    \
            {                                                                \
                float E1 = Aq.x * Bk.x, E2 = Aq.y * Bk.y;                    \
                float E3 = Aq.z * Bk.z, E4 = Aq.w * Bk.w;                    \
                float d1 = E1 + 1.f, d2 = E2 + 1.f;                          \
                float d3 = E3 + 1.f, d4 = E4 + 1.f;                          \
                float n12 = fmaf(w.x, E2, fmaf(w.y, E1, wxy));               \
                float n34 = fmaf(w.z, E4, fmaf(w.w, E3, wzw));               \
                float d12 = d1 * d2, d34 = d3 * d4;                          \
                float num = fmaf(n12, d34, n34 * d12);                       \
                acc = fmaf(num, __builtin_amdgcn_rcpf(d12 * d34), acc);      \
            }
            QUAD(a00, A0, B0);
            QUAD(a01, A0, B1);
            QUAD(a10, A1, B0);
            QUAD(a11, A1, B1);
#undef QUAD
        }
        // no trailing barrier (double-buffered; see proj comment)
    }

    int kA = k0 + ki, kB = kA + 16;
    float p00 = (kA < L) ? __expf(-2.f * a00) : 0.f;
    float p10 = (kA < L) ? __expf(-2.f * a10) : 0.f;
    float p01 = (kB < L) ? __expf(-2.f * a01) : 0.f;
    float p11 = (kB < L) ? __expf(-2.f * a11) : 0.f;

    float* s0 = P + ((size_t)b * NQ + q0 + qi) * NK;
    float* s1 = P + ((size_t)b * NQ + q0 + qi + 16) * NK;
    s0[kA] = p00; s0[kB] = p01;
    s1[kA] = p10; s1[kB] = p11;

    // deterministic per-chunk row sums (reduce over ki = low 4 lane bits)
    float r0s = p00 + p01, r1s = p10 + p11;
#pragma unroll
    for (int o = 1; o <= 8; o <<= 1) {
        r0s += __shfl_xor(r0s, o, 64);
        r1s += __shfl_xor(r1s, o, 64);
    }
    if (ki == 0) {
        Psum[((size_t)b * NQ + q0 + qi) * 32 + kc] = r0s;
        Psum[((size_t)b * NQ + q0 + qi + 16) * 32 + kc] = r1s;
    }
}

// ---------------- K3: PV GEMM + normalize ----------------
// 32q x 32d per block, 4x4 micro, 4-way k-split across waves, register-staged
// double buffering (one barrier per chunk). out = (P @ V) / rowsum.
__global__ __launch_bounds__(256) void pv_kernel(
    const float* __restrict__ P, const float* __restrict__ V,
    const float* __restrict__ Psum, const int* __restrict__ vlen,
    float* __restrict__ out)
{
    __shared__ __align__(16) float sPt[2][32][36];   // [k][q]
    __shared__ __align__(16) float sV[2][32][36];    // [k][d]
    __shared__ float sAll[3][64][17];
    __shared__ float sRowsum[32];

    int bid = blockIdx.x;
    int b = bid & 3;
    int rest = bid >> 2;
    int qt = rest >> 3, dt = rest & 7;
    int q0 = qt * 32, d0 = dt * 32;
    int L = vlen[b];
    int nc = (L + 31) >> 5;

    int tid = threadIdx.x;
    if (tid < 32) {
        float s = 0.f;
        const float* pp = Psum + ((size_t)b * NQ + q0 + tid) * 32;
        for (int c = 0; c < nc; ++c) s += pp[c];
        sRowsum[tid] = s;
    }

    int r = tid >> 3, c4 = tid & 7;
    int w = tid >> 6, sp = tid & 63;
    int qg = sp >> 3, dg = sp & 7;

    const float* Pb = P + ((size_t)b * NQ + q0 + r) * NK;
    const float* Vb = V + (size_t)b * NK * DD + d0;

    float4 pf = *(const float4*)(Pb + c4 * 4);
    float4 vf = *(const float4*)(Vb + (size_t)r * DD + c4 * 4);

    float acc[4][4] = {};

    for (int c = 0; c < nc; ++c) {
        int cur = c & 1;
        sPt[cur][c4 * 4 + 0][r] = pf.x;
        sPt[cur][c4 * 4 + 1][r] = pf.y;
        sPt[cur][c4 * 4 + 2][r] = pf.z;
        sPt[cur][c4 * 4 + 3][r] = pf.w;
        *(float4*)&sV[cur][r][c4 * 4] = vf;
        if (c + 1 < nc) {
            int kn = (c + 1) * 32;
            pf = *(const float4*)(Pb + kn + c4 * 4);
            vf = *(const float4*)(Vb + (size_t)(kn + r) * DD + c4 * 4);
        }
        __syncthreads();
#pragma unroll
        for (int kk = 0; kk < 8; ++kk) {
            float4 A  = *(const float4*)&sPt[cur][w * 8 + kk][qg * 4];
            float4 Bv = *(const float4*)&sV[cur][w * 8 + kk][dg * 4];
            acc[0][0] = fmaf(A.x, Bv.x, acc[0][0]);
            acc[0][1] = fmaf(A.x, Bv.y, acc[0][1]);
            acc[0][2] = fmaf(A.x, Bv.z, acc[0][2]);
            acc[0][3] = fmaf(A.x, Bv.w, acc[0][3]);
            acc[1][0] = fmaf(A.y, Bv.x, acc[1][0]);
            acc[1][1] = fmaf(A.y, Bv.y, acc[1][1]);
            acc[1][2] = fmaf(A.y, Bv.z, acc[1][2]);
            acc[1][3] = fmaf(A.y, Bv.w, acc[1][3]);
            acc[2][0] = fmaf(A.z, Bv.x, acc[2][0]);
            acc[2][1] = fmaf(A.z, Bv.y, acc[2][1]);
            acc[2][2] = fmaf(A.z, Bv.z, acc[2][2]);
            acc[2][3] = fmaf(A.z, Bv.w, acc[2][3]);
            acc[3][0] = fmaf(A.w, Bv.x, acc[3][0]);
            acc[3][1] = fmaf(A.w, Bv.y, acc[3][1]);
            acc[3][2] = fmaf(A.w, Bv.z, acc[3][2]);
            acc[3][3] = fmaf(A.w, Bv.w, acc[3][3]);
        }
        // no trailing barrier (double-buffered)
    }

    if (w > 0) {
#pragma unroll
        for (int i = 0; i < 4; ++i)
#pragma unroll
            for (int j = 0; j < 4; ++j) sAll[w - 1][sp][i * 4 + j] = acc[i][j];
    }
    __syncthreads();
    if (w == 0) {
#pragma unroll
        for (int ww = 0; ww < 3; ++ww)
#pragma unroll
            for (int i = 0; i < 4; ++i)
#pragma unroll
                for (int j = 0; j < 4; ++j) acc[i][j] += sAll[ww][sp][i * 4 + j];
#pragma unroll
        for (int i = 0; i < 4; ++i) {
            float inv = 1.0f / sRowsum[qg * 4 + i];
            float4 o = { acc[i][0] * inv, acc[i][1] * inv,
                         acc[i][2] * inv, acc[i][3] * inv };
            *(float4*)&out[((size_t)b * NQ + q0 + qg * 4 + i) * DD + d0 + dg * 4] = o;
        }
    }
}

extern "C" void kernel_launch(void* const* d_in, const int* in_sizes, int n_in,
                              void* d_out, int out_size, void* d_ws, size_t ws_size,
                              hipStream_t stream) {
    const float* queries = (const float*)d_in[0];  // [B,NQ,D]
    const float* keys    = (const float*)d_in[1];  // [B,NK,D]
    const float* values  = (const float*)d_in[2];  // [B,NK,D]
    const int*   vlens   = (const int*)d_in[3];    // [B]
    const float* Wq      = (const float*)d_in[4];  // [D,H]
    const float* Wk      = (const float*)d_in[5];  // [D,H]
    const float* wv      = (const float*)d_in[6];  // [H]
    float* out = (float*)d_out;

    float* Eqb  = (float*)d_ws;                          // 1 MB
    float* Ekb  = Eqb + (size_t)BB * NQ * HH;            // 4 MB
    float* P    = Ekb + (size_t)BB * NK * HH;            // 4 MB
    float* Psum = P + (size_t)BB * NQ * NK;              // 128 KB [b][q][32]

    dim3 pgrid((BB * NQ) / TM + (BB * NK) / TM, HH / TN);   // (80,4)
    proj_exp_kernel<<<pgrid, 256, 0, stream>>>(queries, keys, Wq, Wk, vlens,
                                               Eqb, Ekb);

    scores_kernel<<<dim3(BB * (NQ / 32) * (NK / 32)), 256, 0, stream>>>(
        Eqb, Ekb, wv, vlens, P, Psum);

    pv_kernel<<<dim3(BB * (NQ / 32) * (DD / 32)), 256, 0, stream>>>(
        P, values, Psum, vlens, out);
}